// Round 6
// baseline (171.164 us; speedup 1.0000x reference)
//
#include <hip/hip_runtime.h>

// Fused Bahdanau context-attention pooling, MI355X (gfx950).
//   K1 prep     : q = query@Wq^T (f32), Wk -> bf16 in ws, mask-layout flag
//   K2 main     : block = 256 thr = 64 rows of kv, processed as 4 sub-tiles
//                 of 16 rows. Staging via global_load_lds width=16 (fire-and-
//                 forget DMA, no VGPR round-trip), DOUBLE-BUFFERED: stage of
//                 sub+1 flies under compute of sub. LDS tile is raw f32 with
//                 source-side XOR swizzle (16B units, u ^= row&7) so MFMA
//                 A-frag ds_read_b128 and ctx reads are conflict-free.
//                 Per-wave a-split (32 cols/wave), online (M,D,ctx) across
//                 subs -> ctxp at 64-row granularity (combines unchanged).
//   K3 combineA : per b: global M, D over 64 group (m,d); scl[j]
//   K4 combineB : context = sum_j scl_j*ctxp_j ; weights = exp(score-M)/D

typedef __attribute__((ext_vector_type(8))) short short8;
typedef __attribute__((ext_vector_type(4))) float f32x4;

#define S_LEN 4096
#define BATCH 32
#define KVD 512
#define AD 128
#define GRP 64                          // rows per block
#define GRPS_PER_B (S_LEN / GRP)        // 64
#define NBLK (BATCH * GRPS_PER_B)       // 2048

// ws byte offsets
#define FLAG_OFF   0
#define Q_OFF      1024
#define WK_OFF     17408       // + 128*512*2 = 131072
#define SCORES_OFF 148480      // + 32*4096*4 = 524288
#define MD_OFF     672768      // + 2048*2*4  = 16384
#define CTXP_OFF   705536      // + 2048*512*4 = 4194304
#define SCL_OFF    9094144     // + 32*64*4   = 8192
#define MD2_OFF    9110528     // + 32*2*4

#define GLOAD_LDS16(gsrc, ldst)                                        \
  __builtin_amdgcn_global_load_lds(                                    \
      (const __attribute__((address_space(1))) void*)(gsrc),           \
      (__attribute__((address_space(3))) void*)(ldst), 16, 0, 0)

__device__ __forceinline__ unsigned short f2bf_rne(float f) {
  unsigned int u = __float_as_uint(f);
  u = (u + 0x7FFFu + ((u >> 16) & 1u)) >> 16;
  return (unsigned short)u;
}
// round-half-up pack of 2 f32 -> 1 dword of 2 bf16 (lo, hi)
__device__ __forceinline__ unsigned int packbf(float a, float b) {
  unsigned int lo = __float_as_uint(a) + 0x8000u;
  unsigned int hi = __float_as_uint(b) + 0x8000u;
  return (lo >> 16) | (hi & 0xFFFF0000u);
}
__device__ __forceinline__ float tanh_fast(float x) {
  return 1.0f - 2.0f / (1.0f + __expf(2.0f * x));
}

__global__ __launch_bounds__(256) void prep_kernel(
    const float* __restrict__ query, const float* __restrict__ Wq,
    const float* __restrict__ Wk, const void* __restrict__ maskp,
    float* __restrict__ qws, unsigned short* __restrict__ wkb,
    int* __restrict__ flagp) {
  int blk = blockIdx.x, t = threadIdx.x;
  if (blk < 32) {
    __shared__ float qrow[KVD];
    qrow[t] = query[blk * KVD + t];
    qrow[t + 256] = query[blk * KVD + t + 256];
    __syncthreads();
    int a = t >> 1, half = t & 1;
    const float4* wq4 = (const float4*)(Wq + (size_t)a * KVD + half * 256);
    const float4* qr4 = (const float4*)(qrow + half * 256);
    float s = 0.f;
#pragma unroll 8
    for (int i = 0; i < 64; ++i) {
      float4 wv = wq4[i], qv = qr4[i];
      s += wv.x * qv.x + wv.y * qv.y + wv.z * qv.z + wv.w * qv.w;
    }
    s += __shfl_xor(s, 1);
    if (half == 0) qws[blk * AD + a] = s;
  } else if (blk < 40) {
    int j = blk - 32;
    const float4* src = (const float4*)Wk;
#pragma unroll 4
    for (int i = 0; i < 8; ++i) {
      int idx4 = j * 2048 + i * 256 + t;
      float4 v = src[idx4];
      ushort4 o;
      o.x = f2bf_rne(v.x); o.y = f2bf_rne(v.y);
      o.z = f2bf_rne(v.z); o.w = f2bf_rne(v.w);
      ((ushort4*)wkb)[idx4] = o;
    }
  } else {
    __shared__ int okv;
    if (t == 0) okv = 1;
    __syncthreads();
    if (t < 128) {
      int wv = ((const int*)maskp)[t];
      if (!(wv == 0 || wv == 1)) okv = 0;
    }
    __syncthreads();
    if (t == 0) flagp[0] = okv;  // 1 = int32 layout, 0 = byte layout
  }
}

__global__ __launch_bounds__(256, 2) void main_kernel(
    const float* __restrict__ kv, const void* __restrict__ maskp,
    const float* __restrict__ Ws, const float* __restrict__ qws,
    const unsigned short* __restrict__ wkb, const int* __restrict__ flagp,
    float* __restrict__ scores, float* __restrict__ md,
    float* __restrict__ ctxp) {
  int t = threadIdx.x;
  int lane = t & 63, w = t >> 6;
  int g = blockIdx.x;                  // 64-row group id
  int b = g >> 6;
  int srow0 = (g & 63) * GRP;          // first row (within b)
  int lr = lane & 15, lg = lane >> 4;

  __shared__ __align__(16) char bufc[2][16 * 2048];  // 2 x (16 rows x 512 f32)
  __shared__ float part[4][16];
  __shared__ float esc2[16];
  __shared__ float bcast[1];

  // block-start loads (L2-hot, overlap with first stage)
  int flag = flagp[0];
  int m64 = 0;
  if (w == 0) {
    int gs = b * S_LEN + srow0 + lane;
    m64 = flag ? ((const int*)maskp)[gs]
               : (int)((const unsigned char*)maskp)[gs];
  }
  float qv0 = qws[b * AD + w * 32 + lr];
  float qv1 = qws[b * AD + w * 32 + 16 + lr];
  float wv0 = Ws[w * 32 + lr];
  float wv1 = Ws[w * 32 + 16 + lr];
  const unsigned short* brow = wkb + (size_t)(w * 32 + lr) * KVD + lg * 8;

  // stage sub-tile (16 rows x 512 f32 = 32KB) into bufc[pbuf] via DMA.
  // unit-linear dest: f = j*256 + w*64 + lane -> dest byte f*16.
  // source swizzle: row = f>>7, u = f&127, src unit = u ^ (row&7).
  auto issue_stage = [&](int sub, int pbuf) {
    const char* base = (const char*)(kv + ((size_t)b * S_LEN + srow0 + sub * 16) * KVD);
    int fl = w * 64 + lane;            // f mod 256 for j=0
#pragma unroll
    for (int j = 0; j < 8; ++j) {
      int f = j * 256 + fl;
      int row = f >> 7, u = f & 127;
      const char* src = base + row * 2048 + ((u ^ (row & 7)) << 4);
      GLOAD_LDS16(src, bufc[pbuf] + j * 4096 + w * 1024);
    }
  };

  issue_stage(0, 0);
  float ctxa = 0.f, ctxb = 0.f;
  float M_run = -INFINITY, D_run = 0.f;

  for (int sub = 0; sub < 4; ++sub) {
    int cur = sub & 1;
    __syncthreads();  // vmcnt(0): buf[cur] staged; prev ctx reads done
    if (sub < 3) issue_stage(sub + 1, cur ^ 1);

    // ---- proj: C[s(16)][a(32 per wave)] = kv @ Wk^T, A from f32 LDS ----
    f32x4 acc0 = (f32x4)0.f, acc1 = (f32x4)0.f;
    const char* rbase = bufc[cur] + lr * 2048;
    int sw = lr & 7;
#pragma unroll 4
    for (int kk = 0; kk < 16; ++kk) {
      int u0 = kk * 8 + lg * 2;
      float4 alo = *(const float4*)(rbase + ((u0 ^ sw) << 4));
      float4 ahi = *(const float4*)(rbase + (((u0 + 1) ^ sw) << 4));
      short8 af;
      ((unsigned int*)&af)[0] = packbf(alo.x, alo.y);
      ((unsigned int*)&af)[1] = packbf(alo.z, alo.w);
      ((unsigned int*)&af)[2] = packbf(ahi.x, ahi.y);
      ((unsigned int*)&af)[3] = packbf(ahi.z, ahi.w);
      short8 bf0 = *(const short8*)(brow + kk * 32);
      short8 bf1 = *(const short8*)(brow + (size_t)16 * KVD + kk * 32);
      acc0 = __builtin_amdgcn_mfma_f32_16x16x32_bf16(af, bf0, acc0, 0, 0, 0);
      acc1 = __builtin_amdgcn_mfma_f32_16x16x32_bf16(af, bf1, acc1, 0, 0, 0);
    }

    // ---- score partials: row r = 4lg+reg, cols a = w*32 + {lr, 16+lr} ----
#pragma unroll
    for (int reg = 0; reg < 4; ++reg) {
      float v = tanh_fast(qv0 + acc0[reg]) * wv0 +
                tanh_fast(qv1 + acc1[reg]) * wv1;
      v += __shfl_xor(v, 1);
      v += __shfl_xor(v, 2);
      v += __shfl_xor(v, 4);
      v += __shfl_xor(v, 8);
      if (lr == 0) part[w][4 * lg + reg] = v;
    }
    __syncthreads();

    // ---- finalize scores + online softmax state (wave 0) ----
    if (w == 0) {
      int r = lane & 15;
      float sc = part[0][r] + part[1][r] + part[2][r] + part[3][r];
      int mk = __shfl(m64, sub * 16 + r);
      sc = mk ? sc : -INFINITY;
      if (lane < 16) scores[b * S_LEN + srow0 + sub * 16 + r] = sc;
      float ms = sc;
      ms = fmaxf(ms, __shfl_xor(ms, 1));
      ms = fmaxf(ms, __shfl_xor(ms, 2));
      ms = fmaxf(ms, __shfl_xor(ms, 4));
      ms = fmaxf(ms, __shfl_xor(ms, 8));
      float Mn = fmaxf(M_run, ms);
      float er = (sc == -INFINITY) ? 0.f : __expf(sc - Mn);
      float ds = er;
      ds += __shfl_xor(ds, 1);
      ds += __shfl_xor(ds, 2);
      ds += __shfl_xor(ds, 4);
      ds += __shfl_xor(ds, 8);
      float rs = (M_run == -INFINITY) ? 0.f : __expf(M_run - Mn);
      D_run = D_run * rs + ds;
      M_run = Mn;
      if (lane < 16) esc2[lane] = er;
      if (lane == 0) bcast[0] = rs;
    }
    __syncthreads();

    // ---- ctx accumulate: thread owns f32 cols {2t, 2t+1} ----
    float rs = bcast[0];
    ctxa *= rs; ctxb *= rs;
    const char* cb = bufc[cur];
    int u = t >> 1, half = (t & 1) * 8;
#pragma unroll 4
    for (int s = 0; s < 16; ++s) {
      float ev = esc2[s];
      float2 vv = *(const float2*)(cb + s * 2048 + ((u ^ (s & 7)) << 4) + half);
      ctxa += ev * vv.x;
      ctxb += ev * vv.y;
    }
  }

  float2 cw; cw.x = ctxa; cw.y = ctxb;
  *(float2*)(ctxp + (size_t)g * KVD + 2 * t) = cw;
  if (t == 0) {
    md[g * 2] = (D_run > 0.f) ? M_run : -INFINITY;
    md[g * 2 + 1] = D_run;
  }
}

__global__ __launch_bounds__(64) void combineA_kernel(
    const float* __restrict__ md, float* __restrict__ scl,
    float* __restrict__ md2) {
  int b = blockIdx.x, t = threadIdx.x;  // 64 threads = 1 wave
  float mv = md[(b * GRPS_PER_B + t) * 2];
  float dv = md[(b * GRPS_PER_B + t) * 2 + 1];
  float m = mv;
  m = fmaxf(m, __shfl_xor(m, 1));
  m = fmaxf(m, __shfl_xor(m, 2));
  m = fmaxf(m, __shfl_xor(m, 4));
  m = fmaxf(m, __shfl_xor(m, 8));
  m = fmaxf(m, __shfl_xor(m, 16));
  m = fmaxf(m, __shfl_xor(m, 32));
  float M = m;
  float e = (dv > 0.f) ? __expf(mv - M) : 0.f;
  float pd = e * dv;
  pd += __shfl_xor(pd, 1);
  pd += __shfl_xor(pd, 2);
  pd += __shfl_xor(pd, 4);
  pd += __shfl_xor(pd, 8);
  pd += __shfl_xor(pd, 16);
  pd += __shfl_xor(pd, 32);
  float D = pd;
  float invD = 1.f / D;
  scl[b * GRPS_PER_B + t] = e * invD;
  if (t == 0) { md2[b * 2] = M; md2[b * 2 + 1] = invD; }
}

__global__ __launch_bounds__(256) void combineB_kernel(
    const float* __restrict__ scl, const float* __restrict__ md2,
    const float* __restrict__ ctxp, const float* __restrict__ scores,
    float* __restrict__ out) {
  int strip = blockIdx.x, b = blockIdx.y, t = threadIdx.x;
  if (strip < 8) {
    __shared__ float part[4][64];
    int c = strip * 64 + (t & 63);
    int jg = t >> 6;
    float sum = 0.f;
    for (int j = jg; j < GRPS_PER_B; j += 4)
      sum += scl[b * GRPS_PER_B + j] *
             ctxp[(size_t)(b * GRPS_PER_B + j) * KVD + c];
    part[jg][t & 63] = sum;
    __syncthreads();
    if (t < 64)
      out[b * KVD + c] = part[0][t] + part[1][t] + part[2][t] + part[3][t];
  } else {
    float M = md2[b * 2], invD = md2[b * 2 + 1];
    int sbase = (strip - 8) * 1024;
#pragma unroll
    for (int i = 0; i < 4; ++i) {
      int s = sbase + i * 256 + t;
      float scv = scores[b * S_LEN + s];
      out[BATCH * KVD + b * S_LEN + s] = __expf(scv - M) * invD;  // -inf -> 0
    }
  }
}

extern "C" void kernel_launch(void* const* d_in, const int* in_sizes, int n_in,
                              void* d_out, int out_size, void* d_ws, size_t ws_size,
                              hipStream_t stream) {
  const float* query = (const float*)d_in[0];
  const float* kv    = (const float*)d_in[1];
  const void*  maskp = d_in[2];
  const float* Wq    = (const float*)d_in[3];
  const float* Wk    = (const float*)d_in[4];
  const float* Ws    = (const float*)d_in[5];
  float* out = (float*)d_out;
  char* w = (char*)d_ws;
  int* flagp = (int*)(w + FLAG_OFF);
  float* qws = (float*)(w + Q_OFF);
  unsigned short* wkb = (unsigned short*)(w + WK_OFF);
  float* scores = (float*)(w + SCORES_OFF);
  float* md = (float*)(w + MD_OFF);
  float* ctxp = (float*)(w + CTXP_OFF);
  float* scl = (float*)(w + SCL_OFF);
  float* md2 = (float*)(w + MD2_OFF);

  prep_kernel<<<41, 256, 0, stream>>>(query, Wq, Wk, maskp, qws, wkb, flagp);
  main_kernel<<<NBLK, 256, 0, stream>>>(kv, maskp, Ws, qws, wkb, flagp,
                                        scores, md, ctxp);
  combineA_kernel<<<BATCH, 64, 0, stream>>>(md, scl, md2);
  combineB_kernel<<<dim3(12, BATCH), 256, 0, stream>>>(scl, md2, ctxp, scores, out);
}